// Round 19
// baseline (34.354 us; speedup 1.0000x reference)
//
#include <hip/hip_runtime.h>
#include <cstdint>
#include <cstddef>

// NetGrad J = W5 D4 W4 D3 W3 D2 W2 D1 W1, output [B,3,64].
// 32 samples/block, 8 waves in a 2x4 ROW-COL split (wg=wave>>2 owns the
// m=wg sample-half: 3 (o,m) A-frags; wc=wave&3 owns 64 cols, FN=4):
// halves per-CU LDS A-read traffic vs pure col-split. B per wave doubles
// (32 frags/phase) but stays coalesced fragment-major + register-prefetched
// in two 16-frag buffers (B0=kc0-3, B1=kc4-7): B1 loads at phase top (hidden
// under kc0-3 MFMAs), B0 reloads mid-phase for the NEXT phase. G lane-exact:
// fwd wave (wg,wc) computes G[m=wg][cols wc] = what bwd wave (wg,wc) needs.

typedef _Float16 half_t;
typedef __attribute__((ext_vector_type(4))) _Float16 half4v;
typedef __attribute__((ext_vector_type(8))) _Float16 half8;
typedef __attribute__((ext_vector_type(4))) float f32x4;

#define MFMA16(a, b, c) __builtin_amdgcn_mfma_f32_16x16x32_f16(a, b, c, 0, 0, 0)

constexpr int Bsz = 8192;
constexpr int LDA = 264;          // LDS row stride in halves (528 B)

// logical k at storage position p (bijection; epilogue writes half4 at
// p = (wc<<6)|(lr<<2)|fn  for logical col j = (wc<<6)|(fn<<4)|lr)
__device__ __forceinline__ int kofp(int p) {
    return (p & 0xC0) | ((p & 3) << 4) | ((p >> 2) & 15);
}

// ---------------- prep: gather-permute to fragment-major f16 tables ----------------
// K=256 tables: chunk (cb,kc), element Q[(cb*8+kc)*512 + lane*8 + e] =
//   V[col = cb*16+(lane&15)][k = kofp(kc*32 + (lane>>4)*8 + e)].
__global__ __launch_bounds__(256)
void prep(const float* __restrict__ W1, const float* __restrict__ W2,
          const float* __restrict__ W3, const float* __restrict__ W4,
          half_t* W1q, half_t* T1q,
          half_t* W2q, half_t* W3q, half_t* W4q,
          half_t* T2q, half_t* T3q, half_t* T4q)
{
    int idx = blockIdx.x * 256 + threadIdx.x;
    if (idx < 16384) {                 // W1q: K=64, linear k; chunk (cb, c2)
        const int cb = idx >> 10, c2 = (idx >> 9) & 1;
        const int lane = (idx >> 3) & 63, e = idx & 7;
        const int col = cb * 16 + (lane & 15);
        const int k = c2 * 32 + (lane >> 4) * 8 + e;
        W1q[idx] = (half_t)W1[col * 64 + k];
        return;
    }
    idx -= 16384;
    if (idx < 16384) {                 // T1q: 64 out-cols, K=256 permuted
        const int cb = idx >> 12, kc = (idx >> 9) & 7;
        const int lane = (idx >> 3) & 63, e = idx & 7;
        const int j = cb * 16 + (lane & 15);
        const int p = kc * 32 + (lane >> 4) * 8 + e;
        T1q[idx] = (half_t)W1[kofp(p) * 64 + j];
        return;
    }
    idx -= 16384;
    if (idx >= 6 * 65536) return;
    const int t = idx >> 16, i = idx & 65535;
    const int cb = i >> 12, kc = (i >> 9) & 7;
    const int lane = (i >> 3) & 63, e = i & 7;
    const int c = cb * 16 + (lane & 15);
    const int p = kc * 32 + (lane >> 4) * 8 + e;
    const int k = kofp(p);
    switch (t) {
        case 0: W2q[i] = (half_t)W2[c * 256 + k]; break;
        case 1: W3q[i] = (half_t)W3[c * 256 + k]; break;
        case 2: W4q[i] = (half_t)W4[c * 256 + k]; break;
        case 3: T2q[i] = (half_t)W2[k * 256 + c]; break;
        case 4: T3q[i] = (half_t)W3[k * 256 + c]; break;
        case 5: T4q[i] = (half_t)W4[k * 256 + c]; break;
    }
}

// ---------------- prefetch helpers ----------------
__device__ __forceinline__
void loadB16(half8 (&B)[16], const half_t* __restrict__ Tq, int cbb, int ko0, int lane)
{
    #pragma unroll
    for (int fn = 0; fn < 4; ++fn)
        #pragma unroll
        for (int kc = 0; kc < 4; ++kc)
            B[fn * 4 + kc] = *(const half8*)(Tq + ((size_t)((cbb + fn) * 8 + ko0 + kc) << 9) + lane * 8);
}
__device__ __forceinline__
void loadT1f(half8 (&B)[16], const half_t* __restrict__ T1q, int wc, int lane)
{
    #pragma unroll
    for (int kc = 0; kc < 8; ++kc)
        B[kc] = *(const half8*)(T1q + ((size_t)(wc * 8 + kc) << 9) + lane * 8);
}

// ---------------- fwd phase (K=256): 1 A-frag (m=wg), FN=4 ----------------
__device__ __forceinline__
void fwd_phase(half8 (&B0)[16], half8 (&B1)[16],
               const half_t* __restrict__ Tcur, const half_t* __restrict__ Tnext,
               const half_t* __restrict__ Ard, half_t* __restrict__ Awr,
               const float* __restrict__ bias, half4v (&gout)[4],
               int wg, int lr, int kgrp, int lane, int cbb, int n0w, int pb4)
{
    loadB16(B1, Tcur, cbb, 4, lane);               // current kc4-7
    float bc[4];
    #pragma unroll
    for (int fn = 0; fn < 4; ++fn) bc[fn] = bias[n0w + fn * 16 + lr];
    const int arow = (wg * 16 + lr) * LDA;
    f32x4 acc[4] = {};
    #pragma unroll
    for (int kc = 0; kc < 4; ++kc) {
        const half8 a = *(const half8*)&Ard[arow + kc * 32 + kgrp * 8];
        __builtin_amdgcn_s_setprio(1);
        #pragma unroll
        for (int fn = 0; fn < 4; ++fn)
            acc[fn] = MFMA16(a, B0[fn * 4 + kc], acc[fn]);
        __builtin_amdgcn_s_setprio(0);
    }
    loadB16(B0, Tnext, cbb, 0, lane);              // next phase kc0-3
    #pragma unroll
    for (int kc = 0; kc < 4; ++kc) {
        const half8 a = *(const half8*)&Ard[arow + (4 + kc) * 32 + kgrp * 8];
        __builtin_amdgcn_s_setprio(1);
        #pragma unroll
        for (int fn = 0; fn < 4; ++fn)
            acc[fn] = MFMA16(a, B1[fn * 4 + kc], acc[fn]);
        __builtin_amdgcn_s_setprio(0);
    }
    #pragma unroll
    for (int r = 0; r < 4; ++r) {
        float g[4], h[4];
        #pragma unroll
        for (int fn = 0; fn < 4; ++fn) {
            const float pre = acc[fn][r] + bc[fn];
            if (pre > 0.f) { g[fn] = 1.f; h[fn] = pre; }
            else           { g[fn] = __expf(pre); h[fn] = g[fn] - 1.f; }
        }
        gout[r] = half4v{(half_t)g[0], (half_t)g[1], (half_t)g[2], (half_t)g[3]};
        half4v w = {(half_t)h[0], (half_t)h[1], (half_t)h[2], (half_t)h[3]};
        *(half4v*)&Awr[(wg * 16 + kgrp * 4 + r) * LDA + pb4] = w;
    }
    __syncthreads();
}

// ---------------- L4 + expand fused ----------------
__device__ __forceinline__
void l4_expand(half8 (&B0)[16], half8 (&B1)[16],
               const half_t* __restrict__ Tcur, const half_t* __restrict__ Tnext,
               const half_t* __restrict__ Ard, half_t* __restrict__ Cwr,
               const float* __restrict__ bias, const float* __restrict__ W5,
               int wg, int lr, int kgrp, int lane, int cbb, int n0w, int pb4)
{
    loadB16(B1, Tcur, cbb, 4, lane);
    float bc[4], w5v[3][4];
    #pragma unroll
    for (int fn = 0; fn < 4; ++fn) {
        const int j = n0w + fn * 16 + lr;
        bc[fn] = bias[j];
        #pragma unroll
        for (int o = 0; o < 3; ++o) w5v[o][fn] = W5[o * 256 + j];
    }
    const int arow = (wg * 16 + lr) * LDA;
    f32x4 acc[4] = {};
    #pragma unroll
    for (int kc = 0; kc < 4; ++kc) {
        const half8 a = *(const half8*)&Ard[arow + kc * 32 + kgrp * 8];
        __builtin_amdgcn_s_setprio(1);
        #pragma unroll
        for (int fn = 0; fn < 4; ++fn)
            acc[fn] = MFMA16(a, B0[fn * 4 + kc], acc[fn]);
        __builtin_amdgcn_s_setprio(0);
    }
    loadB16(B0, Tnext, cbb, 0, lane);
    #pragma unroll
    for (int kc = 0; kc < 4; ++kc) {
        const half8 a = *(const half8*)&Ard[arow + (4 + kc) * 32 + kgrp * 8];
        __builtin_amdgcn_s_setprio(1);
        #pragma unroll
        for (int fn = 0; fn < 4; ++fn)
            acc[fn] = MFMA16(a, B1[fn * 4 + kc], acc[fn]);
        __builtin_amdgcn_s_setprio(0);
    }
    #pragma unroll
    for (int r = 0; r < 4; ++r) {
        float g[4];
        #pragma unroll
        for (int fn = 0; fn < 4; ++fn) {
            const float pre = acc[fn][r] + bc[fn];
            g[fn] = (pre > 0.f) ? 1.f : __expf(pre);
        }
        #pragma unroll
        for (int o = 0; o < 3; ++o) {
            half4v w = {(half_t)(w5v[o][0] * g[0]), (half_t)(w5v[o][1] * g[1]),
                        (half_t)(w5v[o][2] * g[2]), (half_t)(w5v[o][3] * g[3])};
            *(half4v*)&Cwr[(o * 32 + wg * 16 + kgrp * 4 + r) * LDA + pb4] = w;
        }
    }
    __syncthreads();
}

// ---------------- bwd phase: 3 A-frags (o, m=wg), FN=4 ----------------
template<int NEXTMODE>   // 0: B0 <- Tnext kc0-3 ; 1: B0 <- T1q (8 frags, cb=wc)
__device__ __forceinline__
void bwd_phase(half8 (&B0)[16], half8 (&B1)[16],
               const half_t* __restrict__ Tcur, const half_t* __restrict__ Tnext,
               const half_t* __restrict__ Crd, half_t* __restrict__ Cwr,
               const half4v (&gpre)[4],
               int wg, int wc, int lr, int kgrp, int lane, int cbb, int pb4)
{
    loadB16(B1, Tcur, cbb, 4, lane);
    const int ar0 = (wg * 16 + lr) * LDA;
    const int ar1 = (32 + wg * 16 + lr) * LDA;
    const int ar2 = (64 + wg * 16 + lr) * LDA;
    f32x4 acc[3][4] = {};
    #pragma unroll
    for (int kc = 0; kc < 4; ++kc) {
        const int ko = kc * 32 + kgrp * 8;
        const half8 a0 = *(const half8*)&Crd[ar0 + ko];
        const half8 a1 = *(const half8*)&Crd[ar1 + ko];
        const half8 a2 = *(const half8*)&Crd[ar2 + ko];
        __builtin_amdgcn_s_setprio(1);
        #pragma unroll
        for (int fn = 0; fn < 4; ++fn) {
            acc[0][fn] = MFMA16(a0, B0[fn * 4 + kc], acc[0][fn]);
            acc[1][fn] = MFMA16(a1, B0[fn * 4 + kc], acc[1][fn]);
            acc[2][fn] = MFMA16(a2, B0[fn * 4 + kc], acc[2][fn]);
        }
        __builtin_amdgcn_s_setprio(0);
    }
    if constexpr (NEXTMODE == 0) loadB16(B0, Tnext, cbb, 0, lane);
    else                         loadT1f(B0, Tnext, wc, lane);
    #pragma unroll
    for (int kc = 0; kc < 4; ++kc) {
        const int ko = (4 + kc) * 32 + kgrp * 8;
        const half8 a0 = *(const half8*)&Crd[ar0 + ko];
        const half8 a1 = *(const half8*)&Crd[ar1 + ko];
        const half8 a2 = *(const half8*)&Crd[ar2 + ko];
        __builtin_amdgcn_s_setprio(1);
        #pragma unroll
        for (int fn = 0; fn < 4; ++fn) {
            acc[0][fn] = MFMA16(a0, B1[fn * 4 + kc], acc[0][fn]);
            acc[1][fn] = MFMA16(a1, B1[fn * 4 + kc], acc[1][fn]);
            acc[2][fn] = MFMA16(a2, B1[fn * 4 + kc], acc[2][fn]);
        }
        __builtin_amdgcn_s_setprio(0);
    }
    #pragma unroll
    for (int o = 0; o < 3; ++o)
        #pragma unroll
        for (int r = 0; r < 4; ++r) {
            half4v w = {(half_t)(acc[o][0][r] * (float)gpre[r][0]),
                        (half_t)(acc[o][1][r] * (float)gpre[r][1]),
                        (half_t)(acc[o][2][r] * (float)gpre[r][2]),
                        (half_t)(acc[o][3][r] * (float)gpre[r][3])};
            *(half4v*)&Cwr[(o * 32 + wg * 16 + kgrp * 4 + r) * LDA + pb4] = w;
        }
    __syncthreads();
}

// ---------------- fully fused forward+backward, 32 samples / 8 waves (2x4) ----------------
__global__ __launch_bounds__(512, 1)
void netgrad_fused(const float* __restrict__ x,
                   const half_t* __restrict__ W1q, const float* __restrict__ b1,
                   const half_t* __restrict__ W2q, const float* __restrict__ b2,
                   const half_t* __restrict__ W3q, const float* __restrict__ b3,
                   const half_t* __restrict__ W4q, const float* __restrict__ b4,
                   const float* __restrict__ W5,
                   const half_t* __restrict__ T4q, const half_t* __restrict__ T3q,
                   const half_t* __restrict__ T2q, const half_t* __restrict__ T1q,
                   float* __restrict__ out)
{
    __shared__ half_t CA[96 * LDA];
    __shared__ half_t CB[96 * LDA];
    const int tid  = threadIdx.x;
    const int m0s  = blockIdx.x * 32;
    const int lane = tid & 63, lr = lane & 15, kgrp = lane >> 4;
    const int wn   = tid >> 6;
    const int wg   = wn >> 2;              // sample-half (= m)
    const int wc   = wn & 3;               // 64-col group
    const int n0w  = wc * 64;
    const int cbb  = wc * 4;               // base 16-col block
    const int pb4  = (wc << 6) | (lr << 2);

    half8 B0[16], B1[16];
    half4v G1p[4], G2p[4], G3p[4];

    // ---- L1 (K=64 linear): A straight from x (rows m=wg), FN=4 ----
    {
        half8 a[2];
        #pragma unroll
        for (int c2 = 0; c2 < 2; ++c2) {
            const float* xp = x + (size_t)(m0s + wg * 16 + lr) * 64 + c2 * 32 + kgrp * 8;
            const float4 v0 = *(const float4*)xp;
            const float4 v1 = *(const float4*)(xp + 4);
            half8 t;
            t[0] = (half_t)v0.x; t[1] = (half_t)v0.y;
            t[2] = (half_t)v0.z; t[3] = (half_t)v0.w;
            t[4] = (half_t)v1.x; t[5] = (half_t)v1.y;
            t[6] = (half_t)v1.z; t[7] = (half_t)v1.w;
            a[c2] = t;
        }
        half8 w1[4][2];
        #pragma unroll
        for (int fn = 0; fn < 4; ++fn)
            #pragma unroll
            for (int c2 = 0; c2 < 2; ++c2)
                w1[fn][c2] = *(const half8*)(W1q + ((size_t)((cbb + fn) * 2 + c2) << 9) + lane * 8);
        loadB16(B0, W2q, cbb, 0, lane);    // prefetch L2 kc0-3

        f32x4 acc[4] = {};
        #pragma unroll
        for (int c2 = 0; c2 < 2; ++c2)
            #pragma unroll
            for (int fn = 0; fn < 4; ++fn)
                acc[fn] = MFMA16(a[c2], w1[fn][c2], acc[fn]);
        float bc[4];
        #pragma unroll
        for (int fn = 0; fn < 4; ++fn) bc[fn] = b1[n0w + fn * 16 + lr];
        #pragma unroll
        for (int r = 0; r < 4; ++r) {
            float g[4], h[4];
            #pragma unroll
            for (int fn = 0; fn < 4; ++fn) {
                const float pre = acc[fn][r] + bc[fn];
                if (pre > 0.f) { g[fn] = 1.f; h[fn] = pre; }
                else           { g[fn] = __expf(pre); h[fn] = g[fn] - 1.f; }
            }
            G1p[r] = half4v{(half_t)g[0], (half_t)g[1], (half_t)g[2], (half_t)g[3]};
            half4v w = {(half_t)h[0], (half_t)h[1], (half_t)h[2], (half_t)h[3]};
            *(half4v*)&CA[(wg * 16 + kgrp * 4 + r) * LDA + pb4] = w;
        }
        __syncthreads();
    }

    // ---- fwd + bwd pipeline (B0/B1 split-k double buffer) ----
    fwd_phase(B0, B1, W2q, W3q, CA, CB, b2, G2p, wg, lr, kgrp, lane, cbb, n0w, pb4);
    fwd_phase(B0, B1, W3q, W4q, CB, CA, b3, G3p, wg, lr, kgrp, lane, cbb, n0w, pb4);
    l4_expand(B0, B1, W4q, T4q, CA, CB, b4, W5, wg, lr, kgrp, lane, cbb, n0w, pb4);
    bwd_phase<0>(B0, B1, T4q, T3q, CB, CA, G3p, wg, wc, lr, kgrp, lane, cbb, pb4);
    bwd_phase<0>(B0, B1, T3q, T2q, CA, CB, G2p, wg, wc, lr, kgrp, lane, cbb, pb4);
    bwd_phase<1>(B0, B1, T2q, T1q, CB, CA, G1p, wg, wc, lr, kgrp, lane, cbb, pb4);

    // ---- final: CA rows (o, m=wg) @ T1^T -> out cols j = wc*16+lr ----
    {
        const int j = wc * 16 + lr;
        f32x4 acc[3] = {};
        #pragma unroll
        for (int kc = 0; kc < 8; ++kc) {
            const int ko = kc * 32 + kgrp * 8;
            __builtin_amdgcn_s_setprio(1);
            acc[0] = MFMA16(*(const half8*)&CA[(wg * 16 + lr) * LDA + ko],      B0[kc], acc[0]);
            acc[1] = MFMA16(*(const half8*)&CA[(32 + wg * 16 + lr) * LDA + ko], B0[kc], acc[1]);
            acc[2] = MFMA16(*(const half8*)&CA[(64 + wg * 16 + lr) * LDA + ko], B0[kc], acc[2]);
            __builtin_amdgcn_s_setprio(0);
        }
        #pragma unroll
        for (int o = 0; o < 3; ++o)
            #pragma unroll
            for (int r = 0; r < 4; ++r)
                out[((size_t)(m0s + wg * 16 + kgrp * 4 + r) * 3 + o) * 64 + j] = acc[o][r];
    }
}

extern "C" void kernel_launch(void* const* d_in, const int* in_sizes, int n_in,
                              void* d_out, int out_size, void* d_ws, size_t ws_size,
                              hipStream_t stream)
{
    const float* x  = (const float*)d_in[0];
    const float* W1 = (const float*)d_in[1];
    const float* b1 = (const float*)d_in[2];
    const float* W2 = (const float*)d_in[3];
    const float* b2 = (const float*)d_in[4];
    const float* W3 = (const float*)d_in[5];
    const float* b3 = (const float*)d_in[6];
    const float* W4 = (const float*)d_in[7];
    const float* b4 = (const float*)d_in[8];
    const float* W5 = (const float*)d_in[9];

    // ---- workspace carve (~0.9 MB f16 fragment-major tables) ----
    char* p = (char*)d_ws;
    half_t* W1q = (half_t*)p; p += 16384 * 2;
    half_t* T1q = (half_t*)p; p += 16384 * 2;
    half_t* W2q = (half_t*)p; p += 65536 * 2;
    half_t* W3q = (half_t*)p; p += 65536 * 2;
    half_t* W4q = (half_t*)p; p += 65536 * 2;
    half_t* T2q = (half_t*)p; p += 65536 * 2;
    half_t* T3q = (half_t*)p; p += 65536 * 2;
    half_t* T4q = (half_t*)p; p += 65536 * 2;

    const int prep_elems = 16384 + 16384 + 6 * 65536;
    prep<<<(prep_elems + 255) / 256, 256, 0, stream>>>(W1, W2, W3, W4,
        W1q, T1q, W2q, W3q, W4q, T2q, T3q, T4q);

    netgrad_fused<<<Bsz / 32, 512, 0, stream>>>(x,
        W1q, b1,  W2q, b2,  W3q, b3,  W4q, b4,
        W5,  T4q, T3q, T2q, T1q,
        (float*)d_out);
}

// Round 20
// 28.342 us; speedup vs baseline: 1.2121x; 1.2121x over previous
//
#include <hip/hip_runtime.h>
#include <cstdint>
#include <cstddef>

// NetGrad J = W5 D4 W4 D3 W3 D2 W2 D1 W1, output [B,3,64].
// r18 structure (best: 29.4us): 32 samples/block, 8 waves col-split FN=2,
// 1 block/CU, fragment-major coalesced weight tables, permuted LDS columns,
// cross-phase B prefetch in two 16-frag register buffers, G packed half2v.
// This round: setprio REMOVED (m190: negative in barrier-lockstep GEMM).

typedef _Float16 half_t;
typedef __attribute__((ext_vector_type(2))) _Float16 half2v;
typedef __attribute__((ext_vector_type(8))) _Float16 half8;
typedef __attribute__((ext_vector_type(4))) float f32x4;

#define MFMA16(a, b, c) __builtin_amdgcn_mfma_f32_16x16x32_f16(a, b, c, 0, 0, 0)

constexpr int Bsz = 8192;
constexpr int LDA = 264;          // LDS row stride in halves (528 B)

// logical k at storage position p: p bits [7:5]=wn,[4:1]=lr,[0]=fn
__device__ __forceinline__ int kofp(int p) {
    return (p & 0xE0) | ((p & 1) << 4) | ((p >> 1) & 15);
}

// ---------------- prep: gather-permute to fragment-major f16 tables ----------------
__global__ __launch_bounds__(256)
void prep(const float* __restrict__ W1, const float* __restrict__ W2,
          const float* __restrict__ W3, const float* __restrict__ W4,
          half_t* W1q, half_t* T1q,
          half_t* W2q, half_t* W3q, half_t* W4q,
          half_t* T2q, half_t* T3q, half_t* T4q)
{
    int idx = blockIdx.x * 256 + threadIdx.x;
    if (idx < 16384) {                 // W1q: K=64, linear k (cb, c2)
        const int cb = idx >> 10, c2 = (idx >> 9) & 1;
        const int lane = (idx >> 3) & 63, e = idx & 7;
        const int col = cb * 16 + (lane & 15);
        const int k = c2 * 32 + (lane >> 4) * 8 + e;
        W1q[idx] = (half_t)W1[col * 64 + k];
        return;
    }
    idx -= 16384;
    if (idx < 16384) {                 // T1q: 64 cols, K=256 permuted
        const int cb = idx >> 12, kc = (idx >> 9) & 7;
        const int lane = (idx >> 3) & 63, e = idx & 7;
        const int j = cb * 16 + (lane & 15);
        const int p = kc * 32 + (lane >> 4) * 8 + e;
        T1q[idx] = (half_t)W1[kofp(p) * 64 + j];
        return;
    }
    idx -= 16384;
    if (idx >= 6 * 65536) return;
    const int t = idx >> 16, i = idx & 65535;
    const int cb = i >> 12, kc = (i >> 9) & 7;
    const int lane = (i >> 3) & 63, e = i & 7;
    const int c = cb * 16 + (lane & 15);
    const int p = kc * 32 + (lane >> 4) * 8 + e;
    const int k = kofp(p);
    switch (t) {
        case 0: W2q[i] = (half_t)W2[c * 256 + k]; break;
        case 1: W3q[i] = (half_t)W3[c * 256 + k]; break;
        case 2: W4q[i] = (half_t)W4[c * 256 + k]; break;
        case 3: T2q[i] = (half_t)W2[k * 256 + c]; break;
        case 4: T3q[i] = (half_t)W3[k * 256 + c]; break;
        case 5: T4q[i] = (half_t)W4[k * 256 + c]; break;
    }
}

// ---------------- prefetch helpers (coalesced fragment-major loads) ----------------
__device__ __forceinline__
void loadB16(half8 (&B)[16], const half_t* __restrict__ Tq, int cb0, int lane)
{
    #pragma unroll
    for (int fn = 0; fn < 2; ++fn)
        #pragma unroll
        for (int kc = 0; kc < 8; ++kc)
            B[fn * 8 + kc] = *(const half8*)(Tq + ((size_t)((cb0 + fn) * 8 + kc) << 9) + lane * 8);
}

__device__ __forceinline__
void loadB8(half8 (&B)[16], const half_t* __restrict__ Tq, int cb, int lane)
{
    #pragma unroll
    for (int kc = 0; kc < 8; ++kc)
        B[kc] = *(const half8*)(Tq + ((size_t)(cb * 8 + kc) << 9) + lane * 8);
}

// ---------------- fwd phase: preloaded B; G packed half2v; H' -> Awr ----------------
template<bool WRITE_H>
__device__ __forceinline__
void fwd_phase(const half8 (&B)[16],
               const half_t* __restrict__ Ard, half_t* __restrict__ Awr,
               const float* __restrict__ bias, half2v gout[2][4],
               int n0w, int lr, int kgrp, int pb2)
{
    const float bc0 = bias[n0w + lr];
    const float bc1 = bias[n0w + 16 + lr];
    f32x4 acc[2][2] = {};
    #pragma unroll
    for (int kc = 0; kc < 8; ++kc) {
        const int ko = kc * 32 + kgrp * 8;
        half8 a[2];
        #pragma unroll
        for (int m = 0; m < 2; ++m)
            a[m] = *(const half8*)&Ard[(m * 16 + lr) * LDA + ko];
        #pragma unroll
        for (int fn = 0; fn < 2; ++fn)
            #pragma unroll
            for (int m = 0; m < 2; ++m)
                acc[m][fn] = MFMA16(a[m], B[fn * 8 + kc], acc[m][fn]);
    }
    #pragma unroll
    for (int m = 0; m < 2; ++m)
        #pragma unroll
        for (int r = 0; r < 4; ++r) {
            float g[2], h[2];
            #pragma unroll
            for (int fn = 0; fn < 2; ++fn) {
                const float pre = acc[m][fn][r] + (fn ? bc1 : bc0);
                if (pre > 0.f) { g[fn] = 1.f; h[fn] = pre; }
                else           { g[fn] = __expf(pre); h[fn] = g[fn] - 1.f; }
            }
            gout[m][r] = half2v{(half_t)g[0], (half_t)g[1]};
            if constexpr (WRITE_H) {
                half2v w = {(half_t)h[0], (half_t)h[1]};
                *(half2v*)&Awr[(m * 16 + kgrp * 4 + r) * LDA + pb2] = w;
            }
        }
    if constexpr (WRITE_H)
        __syncthreads();
}

// ---------------- bwd phase: preloaded B; 6 A-frags; G from packed half2v ----------------
__device__ __forceinline__
void bwd_phase(const half8 (&B)[16],
               const half_t* __restrict__ Crd, half_t* __restrict__ Cwr,
               const half2v gpre[2][4], int lr, int kgrp, int pb2)
{
    f32x4 acc[3][2][2] = {};
    #pragma unroll
    for (int kc = 0; kc < 8; ++kc) {
        const int ko = kc * 32 + kgrp * 8;
        half8 a[3][2];
        #pragma unroll
        for (int o = 0; o < 3; ++o)
            #pragma unroll
            for (int m = 0; m < 2; ++m)
                a[o][m] = *(const half8*)&Crd[(o * 32 + m * 16 + lr) * LDA + ko];
        #pragma unroll
        for (int fn = 0; fn < 2; ++fn)
            #pragma unroll
            for (int o = 0; o < 3; ++o)
                #pragma unroll
                for (int m = 0; m < 2; ++m)
                    acc[o][m][fn] = MFMA16(a[o][m], B[fn * 8 + kc], acc[o][m][fn]);
    }
    #pragma unroll
    for (int o = 0; o < 3; ++o)
        #pragma unroll
        for (int m = 0; m < 2; ++m)
            #pragma unroll
            for (int r = 0; r < 4; ++r) {
                const float g0 = (float)gpre[m][r][0];
                const float g1 = (float)gpre[m][r][1];
                half2v w = {(half_t)(acc[o][m][0][r] * g0),
                            (half_t)(acc[o][m][1][r] * g1)};
                *(half2v*)&Cwr[(o * 32 + m * 16 + kgrp * 4 + r) * LDA + pb2] = w;
            }
    __syncthreads();
}

// ---------------- fully fused forward+backward, 32 samples / 8 waves ----------------
__global__ __launch_bounds__(512, 1)
void netgrad_fused(const float* __restrict__ x,
                   const half_t* __restrict__ W1q, const float* __restrict__ b1,
                   const half_t* __restrict__ W2q, const float* __restrict__ b2,
                   const half_t* __restrict__ W3q, const float* __restrict__ b3,
                   const half_t* __restrict__ W4q, const float* __restrict__ b4,
                   const float* __restrict__ W5,
                   const half_t* __restrict__ T4q, const half_t* __restrict__ T3q,
                   const half_t* __restrict__ T2q, const half_t* __restrict__ T1q,
                   float* __restrict__ out)
{
    __shared__ half_t CA[96 * LDA];
    __shared__ half_t CB[96 * LDA];
    const int tid  = threadIdx.x;
    const int m0s  = blockIdx.x * 32;
    const int lane = tid & 63, lr = lane & 15, kgrp = lane >> 4;
    const int wn   = tid >> 6;             // wave = col span 0..7
    const int n0w  = wn * 32;
    const int cb0  = wn * 2;
    const int pb2  = (wn << 5) | (lr << 1);

    half8 BA[16], BB[16];
    half2v G1p[2][4], G2p[2][4], G3p[2][4];

    // ---- L1 (K=64) + prologue prefetch of W2 into BA ----
    {
        half8 a[2][2];
        #pragma unroll
        for (int m = 0; m < 2; ++m)
            #pragma unroll
            for (int c2 = 0; c2 < 2; ++c2) {
                const float* xp = x + (size_t)(m0s + m * 16 + lr) * 64 + c2 * 32 + kgrp * 8;
                const float4 v0 = *(const float4*)xp;
                const float4 v1 = *(const float4*)(xp + 4);
                half8 t;
                t[0] = (half_t)v0.x; t[1] = (half_t)v0.y;
                t[2] = (half_t)v0.z; t[3] = (half_t)v0.w;
                t[4] = (half_t)v1.x; t[5] = (half_t)v1.y;
                t[6] = (half_t)v1.z; t[7] = (half_t)v1.w;
                a[m][c2] = t;
            }
        half8 w1[2][2];
        #pragma unroll
        for (int fn = 0; fn < 2; ++fn)
            #pragma unroll
            for (int c2 = 0; c2 < 2; ++c2)
                w1[fn][c2] = *(const half8*)(W1q + ((size_t)((cb0 + fn) * 2 + c2) << 9) + lane * 8);
        loadB16(BA, W2q, cb0, lane);       // prefetch L2 weights

        f32x4 acc[2][2] = {};
        #pragma unroll
        for (int c2 = 0; c2 < 2; ++c2)
            #pragma unroll
            for (int fn = 0; fn < 2; ++fn)
                #pragma unroll
                for (int m = 0; m < 2; ++m)
                    acc[m][fn] = MFMA16(a[m][c2], w1[fn][c2], acc[m][fn]);
        const float bc0 = b1[n0w + lr];
        const float bc1 = b1[n0w + 16 + lr];
        #pragma unroll
        for (int m = 0; m < 2; ++m)
            #pragma unroll
            for (int r = 0; r < 4; ++r) {
                float g[2], h[2];
                #pragma unroll
                for (int fn = 0; fn < 2; ++fn) {
                    const float pre = acc[m][fn][r] + (fn ? bc1 : bc0);
                    if (pre > 0.f) { g[fn] = 1.f; h[fn] = pre; }
                    else           { g[fn] = __expf(pre); h[fn] = g[fn] - 1.f; }
                }
                G1p[m][r] = half2v{(half_t)g[0], (half_t)g[1]};
                half2v w = {(half_t)h[0], (half_t)h[1]};
                *(half2v*)&CA[(m * 16 + kgrp * 4 + r) * LDA + pb2] = w;
            }
        __syncthreads();
    }

    // ---- L2..L4 with rolling prefetch ----
    loadB16(BB, W3q, cb0, lane);
    fwd_phase<true >(BA, CA, CB, b2, G2p, n0w, lr, kgrp, pb2);
    loadB16(BA, W4q, cb0, lane);
    fwd_phase<true >(BB, CB, CA, b3, G3p, n0w, lr, kgrp, pb2);
    loadB16(BB, T4q, cb0, lane);

    // ---- L4 + expand (no H write; expand into CB) ----
    {
        half2v G4p[2][4];
        fwd_phase<false>(BA, CA, nullptr, b4, G4p, n0w, lr, kgrp, pb2);
        float w5v[3][2];
        #pragma unroll
        for (int fn = 0; fn < 2; ++fn) {
            const int k = n0w + fn * 16 + lr;
            #pragma unroll
            for (int o = 0; o < 3; ++o) w5v[o][fn] = W5[o * 256 + k];
        }
        #pragma unroll
        for (int o = 0; o < 3; ++o)
            #pragma unroll
            for (int m = 0; m < 2; ++m)
                #pragma unroll
                for (int r = 0; r < 4; ++r) {
                    half2v w = {(half_t)(w5v[o][0] * (float)G4p[m][r][0]),
                                (half_t)(w5v[o][1] * (float)G4p[m][r][1])};
                    *(half2v*)&CB[(o * 32 + m * 16 + kgrp * 4 + r) * LDA + pb2] = w;
                }
        __syncthreads();
    }

    // ---- backward chain with rolling prefetch: CB -> CA -> CB -> CA ----
    loadB16(BA, T3q, cb0, lane);
    bwd_phase(BB, CB, CA, G3p, lr, kgrp, pb2);
    loadB16(BB, T2q, cb0, lane);
    bwd_phase(BA, CA, CB, G2p, lr, kgrp, pb2);
    loadB8 (BA, T1q, wn & 3, lane);        // final-phase T1 frags (8)
    bwd_phase(BB, CB, CA, G1p, lr, kgrp, pb2);

    // ---- final: CA[96][256] @ T1q^T -> out (B from BA[0..7]) ----
    {
        const int j = (wn & 3) * 16 + lr;
        if (wn < 4) {
            f32x4 acc[2][2] = {};
            #pragma unroll
            for (int kc = 0; kc < 8; ++kc) {
                const int ko = kc * 32 + kgrp * 8;
                #pragma unroll
                for (int o = 0; o < 2; ++o)
                    #pragma unroll
                    for (int m = 0; m < 2; ++m)
                        acc[o][m] = MFMA16(*(const half8*)&CA[(o * 32 + m * 16 + lr) * LDA + ko],
                                           BA[kc], acc[o][m]);
            }
            #pragma unroll
            for (int o = 0; o < 2; ++o)
                #pragma unroll
                for (int m = 0; m < 2; ++m)
                    #pragma unroll
                    for (int r = 0; r < 4; ++r)
                        out[((size_t)(m0s + m * 16 + kgrp * 4 + r) * 3 + o) * 64 + j] = acc[o][m][r];
        } else {
            f32x4 acc[2] = {};
            #pragma unroll
            for (int kc = 0; kc < 8; ++kc) {
                const int ko = kc * 32 + kgrp * 8;
                #pragma unroll
                for (int m = 0; m < 2; ++m)
                    acc[m] = MFMA16(*(const half8*)&CA[(2 * 32 + m * 16 + lr) * LDA + ko],
                                    BA[kc], acc[m]);
            }
            #pragma unroll
            for (int m = 0; m < 2; ++m)
                #pragma unroll
                for (int r = 0; r < 4; ++r)
                    out[((size_t)(m0s + m * 16 + kgrp * 4 + r) * 3 + 2) * 64 + j] = acc[m][r];
        }
    }
}

extern "C" void kernel_launch(void* const* d_in, const int* in_sizes, int n_in,
                              void* d_out, int out_size, void* d_ws, size_t ws_size,
                              hipStream_t stream)
{
    const float* x  = (const float*)d_in[0];
    const float* W1 = (const float*)d_in[1];
    const float* b1 = (const float*)d_in[2];
    const float* W2 = (const float*)d_in[3];
    const float* b2 = (const float*)d_in[4];
    const float* W3 = (const float*)d_in[5];
    const float* b3 = (const float*)d_in[6];
    const float* W4 = (const float*)d_in[7];
    const float* b4 = (const float*)d_in[8];
    const float* W5 = (const float*)d_in[9];

    // ---- workspace carve (~0.9 MB f16 fragment-major tables) ----
    char* p = (char*)d_ws;
    half_t* W1q = (half_t*)p; p += 16384 * 2;
    half_t* T1q = (half_t*)p; p += 16384 * 2;
    half_t* W2q = (half_t*)p; p += 65536 * 2;
    half_t* W3q = (half_t*)p; p += 65536 * 2;
    half_t* W4q = (half_t*)p; p += 65536 * 2;
    half_t* T2q = (half_t*)p; p += 65536 * 2;
    half_t* T3q = (half_t*)p; p += 65536 * 2;
    half_t* T4q = (half_t*)p; p += 65536 * 2;

    const int prep_elems = 16384 + 16384 + 6 * 65536;
    prep<<<(prep_elems + 255) / 256, 256, 0, stream>>>(W1, W2, W3, W4,
        W1q, T1q, W2q, W3q, W4q, T2q, T3q, T4q);

    netgrad_fused<<<Bsz / 32, 512, 0, stream>>>(x,
        W1q, b1,  W2q, b2,  W3q, b3,  W4q, b4,
        W5,  T4q, T3q, T2q, T1q,
        (float*)d_out);
}